// Round 4
// baseline (604.563 us; speedup 1.0000x reference)
//
#include <hip/hip_runtime.h>
#include <hip/hip_cooperative_groups.h>
#include <math.h>

namespace cg = cooperative_groups;

#define NN 20000      // nodes
#define NE 320000     // edges (without self loops)
#define NT 340000     // edges + self loops
#define NG 64         // graphs
#define TPB 256       // 4 waves/block (round-2-proven shape)

using short8  = __attribute__((ext_vector_type(8))) short;   // 8 x bf16 (4 VGPRs)
using float4v = __attribute__((ext_vector_type(4))) float;   // MFMA accumulator

__device__ __forceinline__ float lrelu(float v) { return v > 0.f ? v : 0.2f * v; }
__device__ __forceinline__ float elu1(float v)  { return v > 0.f ? v : (expf(v) - 1.f); }
__device__ __forceinline__ float bflo(unsigned u) { return __uint_as_float(u << 16); }
__device__ __forceinline__ float bfhi(unsigned u) { return __uint_as_float(u & 0xFFFF0000u); }
__device__ __forceinline__ unsigned short f2bf(float f) {
    unsigned u = __float_as_uint(f);
    u += 0x7FFFu + ((u >> 16) & 1u);   // round to nearest even
    return (unsigned short)(u >> 16);
}

#define ACC8(ex, hv) \
    acc[0] = fmaf(ex, bflo(hv.x), acc[0]); \
    acc[1] = fmaf(ex, bfhi(hv.x), acc[1]); \
    acc[2] = fmaf(ex, bflo(hv.y), acc[2]); \
    acc[3] = fmaf(ex, bfhi(hv.y), acc[3]); \
    acc[4] = fmaf(ex, bflo(hv.z), acc[4]); \
    acc[5] = fmaf(ex, bfhi(hv.z), acc[5]); \
    acc[6] = fmaf(ex, bflo(hv.w), acc[6]); \
    acc[7] = fmaf(ex, bfhi(hv.w), acc[7]);

// One cooperative kernel; grid size chosen at launch from the occupancy query so the
// cooperative launch is valid BY CONSTRUCTION. All stages are grid-stride.
// stage0: zero deg/sums + W2->bf16T + a2p GEMVs + gstart + x@W1/logits (independent)
// stage1: hist+scatter fixed-stride CSR
// stage2: layer-1 softmax-agg + elu; layer-2 logits (1 wave / node)
// stage3: layer-2 softmax-agg + MFMA @W2 + elu + graph pool (4 waves / 16-node tile)
// stage4: final GEMM out = (sums/cnt) @ Wo + bo
__global__ __launch_bounds__(TPB, 8) void k_all(
    const int* __restrict__ ei, const float* __restrict__ x,
    const int* __restrict__ batch, const float* __restrict__ W1,
    const float* __restrict__ as1, const float* __restrict__ ad1,
    const float* __restrict__ b1, const float* __restrict__ W2,
    const float* __restrict__ as2, const float* __restrict__ ad2,
    const float* __restrict__ b2, const float* __restrict__ Wo,
    const float* __restrict__ bo,
    int* __restrict__ deg, int* __restrict__ csr64,
    unsigned short* __restrict__ W2bfT,
    float* __restrict__ a2ps, float* __restrict__ a2pd,
    unsigned short* __restrict__ h1bf,
    float* __restrict__ al_s1, float* __restrict__ al_d1,
    unsigned short* __restrict__ o1bf,
    float* __restrict__ al_s2, float* __restrict__ al_d2,
    int* __restrict__ gstart, float* __restrict__ sums,
    float* __restrict__ out)
{
    cg::grid_group gg = cg::this_grid();
    __shared__ __align__(16) char smraw[2304];   // union: lagg[16][72]u16 | part[4][64]f32

    int tid  = threadIdx.x, bid = blockIdx.x;
    int nblk = gridDim.x;
    int nth  = nblk * TPB;                       // total threads (runtime)
    int nwv  = nblk * 4;                         // total waves
    int gtid = bid * TPB + tid;
    int lane = tid & 63, wv = tid >> 6;          // wv in [0,4)
    int gw   = bid * 4 + wv;                     // global wave id
    int e8   = lane >> 3, c8 = lane & 7;         // edge slot, head/channel octet

    // ---------------- stage 0: independent prep ----------------
    for (int i = gtid; i < NN; i += nth) deg[i] = 0;
    for (int i = gtid; i < NG * 512; i += nth) sums[i] = 0.f;
    for (int t = gtid; t < 64 * 512; t += nth) {         // W2 -> bf16 transpose
        int k = t & 63, n = t >> 6;
        W2bfT[t] = f2bf(W2[k * 512 + n]);
    }
    for (int t = gw; t < 128; t += nwv) {                // a2p[k] = sum_j W2[k][j]*a[j]
        int which = t >> 6, k = t & 63;
        const float* av = which ? ad2 : as2;
        float s = 0.f;
        for (int j = lane; j < 512; j += 64) s = fmaf(W2[k * 512 + j], av[j], s);
#pragma unroll
        for (int o = 32; o >= 1; o >>= 1) s += __shfl_xor(s, o, 64);
        if (lane == 0) (which ? a2pd : a2ps)[k] = s;
    }
    for (int i = gtid; i <= NG; i += nth) {              // per-graph starts (batch sorted)
        int lo = 0, hi = NN;
        while (lo < hi) {
            int mid = (lo + hi) >> 1;
            if (batch[mid] < i) lo = mid + 1; else hi = mid;
        }
        gstart[i] = lo;
    }
    for (int t = gtid; t < NN * 64; t += nth) {          // x@W1 + layer-1 logits
        int n = t >> 6, j = t & 63;                      // stride is x64 -> j == lane
        float x0 = x[n * 3 + 0], x1 = x[n * 3 + 1], x2 = x[n * 3 + 2];
        float v = fmaf(x0, W1[j], fmaf(x1, W1[64 + j], x2 * W1[128 + j]));
        h1bf[n * 64 + j] = f2bf(v);
        float ps = v * as1[j], pd = v * ad1[j];
        for (int o = 4; o >= 1; o >>= 1) {
            ps += __shfl_xor(ps, o, 8);
            pd += __shfl_xor(pd, o, 8);
        }
        if ((j & 7) == 0) {
            al_s1[n * 8 + (j >> 3)] = ps;
            al_d1[n * 8 + (j >> 3)] = pd;
        }
    }
    gg.sync();

    // ---------------- stage 1: hist + scatter (fixed-stride CSR) ----------------
    for (int t = gtid; t < NT; t += nth) {
        int s, d;
        if (t < NE) { s = ei[t]; d = ei[NE + t]; }
        else        { s = d = t - NE; }                  // self loop
        int r = atomicAdd(&deg[d], 1);
        if (r < 64) csr64[(d << 6) + r] = s;
    }
    gg.sync();

    // ---------------- stage 2: layer-1 softmax-agg + elu; layer-2 logits ----------------
    for (int n = gw; n < NN; n += nwv) {
        int dg = deg[n]; dg = dg < 64 ? dg : 64;
        int sAll = csr64[(n << 6) + (lane < dg ? lane : 0)];
        float ald = al_d1[n * 8 + c8];
        float acc[8] = {0.f, 0.f, 0.f, 0.f, 0.f, 0.f, 0.f, 0.f};
        float dsum = 0.f;
        for (int base = 0; base < dg; base += 16) {
            int sA = __shfl(sAll, base + e8, 64);
            int sB = __shfl(sAll, base + 8 + e8, 64);
            float exA = 0.f, exB = 0.f;
            if (base + e8 < dg)     exA = __expf(lrelu(al_s1[sA * 8 + c8] + ald));
            if (base + 8 + e8 < dg) exB = __expf(lrelu(al_s1[sB * 8 + c8] + ald));
            dsum += exA + exB;
            uint4 hA = *(const uint4*)(h1bf + sA * 64 + c8 * 8);
            uint4 hB = *(const uint4*)(h1bf + sB * 64 + c8 * 8);
            ACC8(exA, hA);
            ACC8(exB, hB);
        }
#pragma unroll
        for (int o = 32; o >= 8; o >>= 1) {
#pragma unroll
            for (int k = 0; k < 8; ++k) acc[k] += __shfl_xor(acc[k], o, 64);
            dsum += __shfl_xor(dsum, o, 64);
        }
        if (e8 == 0) {   // lanes 0..7: finalize head c8's 8 channels
            float inv = 1.f / dsum;
            const float* bp = b1 + c8 * 8;
            float v[8];
#pragma unroll
            for (int k = 0; k < 8; ++k) v[k] = elu1(acc[k] * inv + bp[k]);
            uint4 pk;
            pk.x = (unsigned)f2bf(v[0]) | ((unsigned)f2bf(v[1]) << 16);
            pk.y = (unsigned)f2bf(v[2]) | ((unsigned)f2bf(v[3]) << 16);
            pk.z = (unsigned)f2bf(v[4]) | ((unsigned)f2bf(v[5]) << 16);
            pk.w = (unsigned)f2bf(v[6]) | ((unsigned)f2bf(v[7]) << 16);
            *(uint4*)(o1bf + n * 64 + c8 * 8) = pk;
            float ps = 0.f, pd = 0.f;
            const float* asp = a2ps + c8 * 8;
            const float* adp = a2pd + c8 * 8;
#pragma unroll
            for (int k = 0; k < 8; ++k) {
                ps = fmaf(v[k], asp[k], ps);
                pd = fmaf(v[k], adp[k], pd);
            }
            for (int o = 4; o >= 1; o >>= 1) {
                ps += __shfl_xor(ps, o, 8);
                pd += __shfl_xor(pd, o, 8);
            }
            if (c8 == 0) { al_s2[n] = ps; al_d2[n] = pd; }
        }
    }
    gg.sync();

    // ---------------- stage 3: layer-2 softmax-agg + MFMA @W2 + elu + pool ----------------
    {
        unsigned short (*lagg)[72] = (unsigned short(*)[72])smraw;   // padded rows: 144B
        for (int tile = bid; tile < NN / 16; tile += nblk) {
            int n0 = tile * 16;
#pragma unroll
            for (int i = 0; i < 4; ++i) {      // phase A: wave wv owns rows wv*4..wv*4+3
                int r = wv * 4 + i;
                int n = n0 + r;
                float ald = al_d2[n];
                int dg = deg[n]; dg = dg < 64 ? dg : 64;
                int sAll = csr64[(n << 6) + (lane < dg ? lane : 0)];
                float exAll = 0.f;
                if (lane < dg) exAll = __expf(lrelu(al_s2[sAll] + ald));
                float dsum = exAll;
                dsum += __shfl_xor(dsum, 1, 64);
                dsum += __shfl_xor(dsum, 2, 64);
                dsum += __shfl_xor(dsum, 4, 64);
                float acc[8] = {0.f, 0.f, 0.f, 0.f, 0.f, 0.f, 0.f, 0.f};
                for (int base = 0; base < dg; base += 16) {
                    int sA    = __shfl(sAll, base + e8, 64);
                    int sB    = __shfl(sAll, base + 8 + e8, 64);
                    float exA = __shfl(exAll, base + e8, 64);   // 0 for invalid slots
                    float exB = __shfl(exAll, base + 8 + e8, 64);
                    uint4 hA = *(const uint4*)(o1bf + sA * 64 + c8 * 8);
                    uint4 hB = *(const uint4*)(o1bf + sB * 64 + c8 * 8);
                    ACC8(exA, hA);
                    ACC8(exB, hB);
                }
#pragma unroll
                for (int o = 32; o >= 8; o >>= 1) {
#pragma unroll
                    for (int k = 0; k < 8; ++k) acc[k] += __shfl_xor(acc[k], o, 64);
                    dsum += __shfl_xor(dsum, o, 64);
                }
                if (e8 == 0) {
                    float inv = 1.f / dsum;
                    uint4 pk;
                    pk.x = (unsigned)f2bf(acc[0] * inv) | ((unsigned)f2bf(acc[1] * inv) << 16);
                    pk.y = (unsigned)f2bf(acc[2] * inv) | ((unsigned)f2bf(acc[3] * inv) << 16);
                    pk.z = (unsigned)f2bf(acc[4] * inv) | ((unsigned)f2bf(acc[5] * inv) << 16);
                    pk.w = (unsigned)f2bf(acc[6] * inv) | ((unsigned)f2bf(acc[7] * inv) << 16);
                    *(uint4*)&lagg[r][c8 * 8] = pk;
                }
            }
            __syncthreads();
            // phase B: A[m][k] from LDS; B[k][n] from W2bfT (n-major)
            int mcol = lane & 15;
            int q = lane >> 4;
            short8 a0 = *(const short8*)&lagg[mcol][q * 8];
            short8 a1 = *(const short8*)&lagg[mcol][32 + q * 8];
            __syncthreads();   // lagg in regs -> safe to overwrite next tile
            int gmin = batch[n0], gmax = batch[n0 + 15];
            int batchq[4];
#pragma unroll
            for (int r = 0; r < 4; ++r) batchq[r] = batch[n0 + q * 4 + r];
#pragma unroll
            for (int t = 0; t < 8; ++t) {
                int c = wv * 128 + t * 16 + mcol;
                const unsigned short* bp = W2bfT + c * 64 + q * 8;
                short8 b0  = *(const short8*)bp;
                short8 b1v = *(const short8*)(bp + 32);
                float4v macc = {0.f, 0.f, 0.f, 0.f};
                macc = __builtin_amdgcn_mfma_f32_16x16x32_bf16(a0, b0, macc, 0, 0, 0);
                macc = __builtin_amdgcn_mfma_f32_16x16x32_bf16(a1, b1v, macc, 0, 0, 0);
                float bias = b2[c];
                float val[4];
#pragma unroll
                for (int r = 0; r < 4; ++r) val[r] = elu1(macc[r] + bias);
                for (int g = gmin; g <= gmax; ++g) {
                    float s = 0.f;
#pragma unroll
                    for (int r = 0; r < 4; ++r) s += (batchq[r] == g) ? val[r] : 0.f;
                    s += __shfl_xor(s, 16, 64);   // reduce across the 4 quads
                    s += __shfl_xor(s, 32, 64);
                    if (q == 0) atomicAdd(&sums[g * 512 + c], s);
                }
            }
        }
    }
    gg.sync();

    // ---------------- stage 4: final GEMM out[g][j] = (sums[g]/cnt[g]) @ Wo + bo ----------------
    {
        float (*part)[64] = (float(*)[64])smraw;
        for (int work = bid; work < NG * 8; work += nblk) {
            int g = work >> 3, jo = work & 7;       // 64 g x 8 j-chunks
            int j = jo * 64 + lane;
            const float* srow = sums + g * 512;
            float acc = 0.f;
            for (int k = wv * 128; k < wv * 128 + 128; ++k)   // 4 waves split k
                acc = fmaf(srow[k], Wo[k * 512 + j], acc);
            part[wv][lane] = acc;
            __syncthreads();
            if (tid < 64) {
                float s = part[0][tid] + part[1][tid] + part[2][tid] + part[3][tid];
                float c = (float)(gstart[g + 1] - gstart[g]);
                float inv = 1.f / (c > 0.f ? c : 1.f);
                out[g * 512 + jo * 64 + tid] = fmaf(s, inv, bo[jo * 64 + tid]);
            }
            __syncthreads();   // part reused next iteration
        }
    }
}

extern "C" void kernel_launch(void* const* d_in, const int* in_sizes, int n_in,
                              void* d_out, int out_size, void* d_ws, size_t ws_size,
                              hipStream_t stream) {
    const float* x     = (const float*)d_in[0];
    const int*   ei    = (const int*)d_in[1];    // [2, NE]
    const int*   batch = (const int*)d_in[2];    // [NN] sorted
    const float* W1    = (const float*)d_in[3];
    const float* as1   = (const float*)d_in[4];
    const float* ad1   = (const float*)d_in[5];
    const float* b1    = (const float*)d_in[6];
    const float* W2    = (const float*)d_in[7];
    const float* as2   = (const float*)d_in[8];
    const float* ad2   = (const float*)d_in[9];
    const float* b2    = (const float*)d_in[10];
    const float* Wo    = (const float*)d_in[11];
    const float* bo    = (const float*)d_in[12];
    float* out = (float*)d_out;

    // ---- workspace arena (4-byte units) ----
    float* w = (float*)d_ws;
    unsigned short* h1bf  = (unsigned short*)(w + 0);        // 640,000 units
    float* al_s1 = w + 640000;     // 160,000
    float* al_d1 = w + 800000;     // 160,000
    unsigned short* o1bf  = (unsigned short*)(w + 960000);   // 640,000 units (16B aligned)
    unsigned short* W2bfT = (unsigned short*)(w + 1600000);  // 16,384 units (16B aligned)
    float* a2ps  = w + 1616384;    // 64
    float* a2pd  = w + 1616448;    // 64
    float* al_s2 = w + 1616512;    // 20,000
    float* al_d2 = w + 1636512;    // 20,000
    int*   gstart = (int*)(w + 1656512);   // 65
    int*   csr64  = (int*)(w + 1656580);   // 1,280,000 (fixed-stride CSR, 64 slots/node)
    float* sums   = w + 2936580;           // 32,768 (16B aligned; zeroed in stage 0)
    int*   deg    = (int*)(w + 2969348);   // 20,000 (zeroed in stage 0)
    // end: 2,989,348 units ≈ 12.0 MB

    // Grid sized from the occupancy query so the cooperative launch is always valid.
    static int g_grid = 0;
    if (g_grid == 0) {
        hipDeviceProp_t prop;
        hipGetDeviceProperties(&prop, 0);
        int maxBlk = 0;
        hipOccupancyMaxActiveBlocksPerMultiprocessor(&maxBlk, k_all, TPB, 0);
        if (maxBlk < 1) maxBlk = 1;
        long g = (long)maxBlk * (long)prop.multiProcessorCount;
        if (g > 2048) g = 2048;   // enough TLP; beyond this the loops just shrink
        if (g < 64)   g = 64;
        g_grid = (int)g;
    }

    void* args[] = {
        (void*)&ei, (void*)&x, (void*)&batch, (void*)&W1, (void*)&as1, (void*)&ad1,
        (void*)&b1, (void*)&W2, (void*)&as2, (void*)&ad2, (void*)&b2, (void*)&Wo,
        (void*)&bo, (void*)&deg, (void*)&csr64, (void*)&W2bfT, (void*)&a2ps,
        (void*)&a2pd, (void*)&h1bf, (void*)&al_s1, (void*)&al_d1, (void*)&o1bf,
        (void*)&al_s2, (void*)&al_d2, (void*)&gstart, (void*)&sums, (void*)&out
    };
    hipLaunchCooperativeKernel((const void*)k_all, dim3(g_grid), dim3(TPB), args, 0, stream);
}

// Round 5
// 423.900 us; speedup vs baseline: 1.4262x; 1.4262x over previous
//
#include <hip/hip_runtime.h>
#include <hip/hip_cooperative_groups.h>
#include <math.h>

namespace cg = cooperative_groups;

#define NN 20000      // nodes
#define NE 320000     // edges (without self loops)
#define NT 340000     // edges + self loops
#define NG 64         // graphs
#define TPB 256       // 4 waves/block

using short8  = __attribute__((ext_vector_type(8))) short;   // 8 x bf16 (4 VGPRs)
using float4v = __attribute__((ext_vector_type(4))) float;   // MFMA accumulator

__device__ __forceinline__ float lrelu(float v) { return v > 0.f ? v : 0.2f * v; }
__device__ __forceinline__ float elu1(float v)  { return v > 0.f ? v : (expf(v) - 1.f); }
__device__ __forceinline__ float bflo(unsigned u) { return __uint_as_float(u << 16); }
__device__ __forceinline__ float bfhi(unsigned u) { return __uint_as_float(u & 0xFFFF0000u); }
__device__ __forceinline__ unsigned short f2bf(float f) {
    unsigned u = __float_as_uint(f);
    u += 0x7FFFu + ((u >> 16) & 1u);   // round to nearest even
    return (unsigned short)(u >> 16);
}

#define ACC8(ex, hv) \
    acc[0] = fmaf(ex, bflo(hv.x), acc[0]); \
    acc[1] = fmaf(ex, bfhi(hv.x), acc[1]); \
    acc[2] = fmaf(ex, bflo(hv.y), acc[2]); \
    acc[3] = fmaf(ex, bfhi(hv.y), acc[3]); \
    acc[4] = fmaf(ex, bflo(hv.z), acc[4]); \
    acc[5] = fmaf(ex, bfhi(hv.z), acc[5]); \
    acc[6] = fmaf(ex, bflo(hv.w), acc[6]); \
    acc[7] = fmaf(ex, bfhi(hv.w), acc[7]);

// One cooperative kernel; grid sized from the occupancy query (always-valid launch).
// launch_bounds(256,4): VGPR cap 64 -> compiler's natural ~44 fits SPILL-FREE (round 4's
// (256,8) forced a 32-VGPR cap -> scratch spills -> 2x HBM traffic, 3% VALUBusy).
// HW can still co-schedule 8 blocks/CU at <=64 VGPR (waves/CU ~ 2048/VGPR).
__global__ __launch_bounds__(TPB, 4) void k_all(
    const int* __restrict__ ei, const float* __restrict__ x,
    const int* __restrict__ batch, const float* __restrict__ W1,
    const float* __restrict__ as1, const float* __restrict__ ad1,
    const float* __restrict__ b1, const float* __restrict__ W2,
    const float* __restrict__ as2, const float* __restrict__ ad2,
    const float* __restrict__ b2, const float* __restrict__ Wo,
    const float* __restrict__ bo,
    int* __restrict__ deg, int* __restrict__ csr64,
    unsigned short* __restrict__ W2bfT,
    float* __restrict__ a2ps, float* __restrict__ a2pd,
    unsigned short* __restrict__ h1bf,
    float* __restrict__ al_s1, float* __restrict__ al_d1,
    unsigned short* __restrict__ o1bf,
    float* __restrict__ al_s2, float* __restrict__ al_d2,
    int* __restrict__ gstart, float* __restrict__ sums,
    float* __restrict__ out)
{
    cg::grid_group gg = cg::this_grid();
    __shared__ __align__(16) char smraw[2304];   // union: lagg[16][72]u16 | part[4][64]f32

    int tid  = threadIdx.x, bid = blockIdx.x;
    int nblk = gridDim.x;
    int nth  = nblk * TPB;                       // total threads (runtime)
    int nwv  = nblk * 4;                         // total waves
    int gtid = bid * TPB + tid;
    int lane = tid & 63, wv = tid >> 6;          // wv in [0,4)
    int gw   = bid * 4 + wv;                     // global wave id
    int e8   = lane >> 3, c8 = lane & 7;         // edge slot, head/channel octet

    // ---------------- stage 0: independent prep ----------------
    for (int i = gtid; i < NN; i += nth) deg[i] = 0;
    for (int i = gtid; i < NG * 512; i += nth) sums[i] = 0.f;
    for (int t = gtid; t < 64 * 512; t += nth) {         // W2 -> bf16 transpose
        int k = t & 63, n = t >> 6;
        W2bfT[t] = f2bf(W2[k * 512 + n]);
    }
    for (int t = gw; t < 128; t += nwv) {                // a2p[k] = sum_j W2[k][j]*a[j]
        int which = t >> 6, k = t & 63;
        const float* av = which ? ad2 : as2;
        float s = 0.f;
        for (int j = lane; j < 512; j += 64) s = fmaf(W2[k * 512 + j], av[j], s);
#pragma unroll
        for (int o = 32; o >= 1; o >>= 1) s += __shfl_xor(s, o, 64);
        if (lane == 0) (which ? a2pd : a2ps)[k] = s;
    }
    for (int i = gtid; i <= NG; i += nth) {              // per-graph starts (batch sorted)
        int lo = 0, hi = NN;
        while (lo < hi) {
            int mid = (lo + hi) >> 1;
            if (batch[mid] < i) lo = mid + 1; else hi = mid;
        }
        gstart[i] = lo;
    }
    for (int t = gtid; t < NN * 64; t += nth) {          // x@W1 + layer-1 logits
        int n = t >> 6, j = t & 63;                      // stride is x64 -> j == lane
        float x0 = x[n * 3 + 0], x1 = x[n * 3 + 1], x2 = x[n * 3 + 2];
        float v = fmaf(x0, W1[j], fmaf(x1, W1[64 + j], x2 * W1[128 + j]));
        h1bf[n * 64 + j] = f2bf(v);
        float ps = v * as1[j], pd = v * ad1[j];
        for (int o = 4; o >= 1; o >>= 1) {
            ps += __shfl_xor(ps, o, 8);
            pd += __shfl_xor(pd, o, 8);
        }
        if ((j & 7) == 0) {
            al_s1[n * 8 + (j >> 3)] = ps;
            al_d1[n * 8 + (j >> 3)] = pd;
        }
    }
    gg.sync();

    // ---------------- stage 1: hist + scatter (fixed-stride CSR) ----------------
    for (int t = gtid; t < NT; t += nth) {
        int s, d;
        if (t < NE) { s = ei[t]; d = ei[NE + t]; }
        else        { s = d = t - NE; }                  // self loop
        int r = atomicAdd(&deg[d], 1);
        if (r < 64) csr64[(d << 6) + r] = s;
    }
    gg.sync();

    // ---------------- stage 2: layer-1 softmax-agg + elu; layer-2 logits ----------------
    for (int n = gw; n < NN; n += nwv) {
        int dg = deg[n]; dg = dg < 64 ? dg : 64;
        int sAll = csr64[(n << 6) + (lane < dg ? lane : 0)];
        float ald = al_d1[n * 8 + c8];
        float acc[8] = {0.f, 0.f, 0.f, 0.f, 0.f, 0.f, 0.f, 0.f};
        float dsum = 0.f;
        for (int base = 0; base < dg; base += 16) {
            int sA = __shfl(sAll, base + e8, 64);
            int sB = __shfl(sAll, base + 8 + e8, 64);
            float exA = 0.f, exB = 0.f;
            if (base + e8 < dg)     exA = __expf(lrelu(al_s1[sA * 8 + c8] + ald));
            if (base + 8 + e8 < dg) exB = __expf(lrelu(al_s1[sB * 8 + c8] + ald));
            dsum += exA + exB;
            uint4 hA = *(const uint4*)(h1bf + sA * 64 + c8 * 8);
            uint4 hB = *(const uint4*)(h1bf + sB * 64 + c8 * 8);
            ACC8(exA, hA);
            ACC8(exB, hB);
        }
#pragma unroll
        for (int o = 32; o >= 8; o >>= 1) {
#pragma unroll
            for (int k = 0; k < 8; ++k) acc[k] += __shfl_xor(acc[k], o, 64);
            dsum += __shfl_xor(dsum, o, 64);
        }
        if (e8 == 0) {   // lanes 0..7: finalize head c8's 8 channels
            float inv = 1.f / dsum;
            const float* bp = b1 + c8 * 8;
            float v[8];
#pragma unroll
            for (int k = 0; k < 8; ++k) v[k] = elu1(acc[k] * inv + bp[k]);
            uint4 pk;
            pk.x = (unsigned)f2bf(v[0]) | ((unsigned)f2bf(v[1]) << 16);
            pk.y = (unsigned)f2bf(v[2]) | ((unsigned)f2bf(v[3]) << 16);
            pk.z = (unsigned)f2bf(v[4]) | ((unsigned)f2bf(v[5]) << 16);
            pk.w = (unsigned)f2bf(v[6]) | ((unsigned)f2bf(v[7]) << 16);
            *(uint4*)(o1bf + n * 64 + c8 * 8) = pk;
            float ps = 0.f, pd = 0.f;
            const float* asp = a2ps + c8 * 8;
            const float* adp = a2pd + c8 * 8;
#pragma unroll
            for (int k = 0; k < 8; ++k) {
                ps = fmaf(v[k], asp[k], ps);
                pd = fmaf(v[k], adp[k], pd);
            }
            for (int o = 4; o >= 1; o >>= 1) {
                ps += __shfl_xor(ps, o, 8);
                pd += __shfl_xor(pd, o, 8);
            }
            if (c8 == 0) { al_s2[n] = ps; al_d2[n] = pd; }
        }
    }
    gg.sync();

    // ---------------- stage 3: layer-2 softmax-agg + MFMA @W2 + elu + pool ----------------
    {
        unsigned short (*lagg)[72] = (unsigned short(*)[72])smraw;   // padded rows: 144B
        for (int tile = bid; tile < NN / 16; tile += nblk) {
            int n0 = tile * 16;
#pragma unroll
            for (int i = 0; i < 4; ++i) {      // phase A: wave wv owns rows wv*4..wv*4+3
                int r = wv * 4 + i;
                int n = n0 + r;
                float ald = al_d2[n];
                int dg = deg[n]; dg = dg < 64 ? dg : 64;
                int sAll = csr64[(n << 6) + (lane < dg ? lane : 0)];
                float exAll = 0.f;
                if (lane < dg) exAll = __expf(lrelu(al_s2[sAll] + ald));
                float dsum = exAll;
                dsum += __shfl_xor(dsum, 1, 64);
                dsum += __shfl_xor(dsum, 2, 64);
                dsum += __shfl_xor(dsum, 4, 64);
                float acc[8] = {0.f, 0.f, 0.f, 0.f, 0.f, 0.f, 0.f, 0.f};
                for (int base = 0; base < dg; base += 16) {
                    int sA    = __shfl(sAll, base + e8, 64);
                    int sB    = __shfl(sAll, base + 8 + e8, 64);
                    float exA = __shfl(exAll, base + e8, 64);   // 0 for invalid slots
                    float exB = __shfl(exAll, base + 8 + e8, 64);
                    uint4 hA = *(const uint4*)(o1bf + sA * 64 + c8 * 8);
                    uint4 hB = *(const uint4*)(o1bf + sB * 64 + c8 * 8);
                    ACC8(exA, hA);
                    ACC8(exB, hB);
                }
#pragma unroll
                for (int o = 32; o >= 8; o >>= 1) {
#pragma unroll
                    for (int k = 0; k < 8; ++k) acc[k] += __shfl_xor(acc[k], o, 64);
                    dsum += __shfl_xor(dsum, o, 64);
                }
                if (e8 == 0) {
                    float inv = 1.f / dsum;
                    uint4 pk;
                    pk.x = (unsigned)f2bf(acc[0] * inv) | ((unsigned)f2bf(acc[1] * inv) << 16);
                    pk.y = (unsigned)f2bf(acc[2] * inv) | ((unsigned)f2bf(acc[3] * inv) << 16);
                    pk.z = (unsigned)f2bf(acc[4] * inv) | ((unsigned)f2bf(acc[5] * inv) << 16);
                    pk.w = (unsigned)f2bf(acc[6] * inv) | ((unsigned)f2bf(acc[7] * inv) << 16);
                    *(uint4*)&lagg[r][c8 * 8] = pk;
                }
            }
            __syncthreads();
            // phase B: A[m][k] from LDS; B[k][n] from W2bfT (n-major)
            int mcol = lane & 15;
            int q = lane >> 4;
            short8 a0 = *(const short8*)&lagg[mcol][q * 8];
            short8 a1 = *(const short8*)&lagg[mcol][32 + q * 8];
            __syncthreads();   // lagg in regs -> safe to overwrite next tile
            int gmin = batch[n0], gmax = batch[n0 + 15];
            int batchq[4];
#pragma unroll
            for (int r = 0; r < 4; ++r) batchq[r] = batch[n0 + q * 4 + r];
#pragma unroll
            for (int t = 0; t < 8; ++t) {
                int c = wv * 128 + t * 16 + mcol;
                const unsigned short* bp = W2bfT + c * 64 + q * 8;
                short8 b0  = *(const short8*)bp;
                short8 b1v = *(const short8*)(bp + 32);
                float4v macc = {0.f, 0.f, 0.f, 0.f};
                macc = __builtin_amdgcn_mfma_f32_16x16x32_bf16(a0, b0, macc, 0, 0, 0);
                macc = __builtin_amdgcn_mfma_f32_16x16x32_bf16(a1, b1v, macc, 0, 0, 0);
                float bias = b2[c];
                float val[4];
#pragma unroll
                for (int r = 0; r < 4; ++r) val[r] = elu1(macc[r] + bias);
                for (int g = gmin; g <= gmax; ++g) {
                    float s = 0.f;
#pragma unroll
                    for (int r = 0; r < 4; ++r) s += (batchq[r] == g) ? val[r] : 0.f;
                    s += __shfl_xor(s, 16, 64);   // reduce across the 4 quads
                    s += __shfl_xor(s, 32, 64);
                    if (q == 0) atomicAdd(&sums[g * 512 + c], s);
                }
            }
        }
    }
    gg.sync();

    // ---------------- stage 4: final GEMM out[g][j] = (sums[g]/cnt[g]) @ Wo + bo ----------------
    {
        float (*part)[64] = (float(*)[64])smraw;
        for (int work = bid; work < NG * 8; work += nblk) {
            int g = work >> 3, jo = work & 7;       // 64 g x 8 j-chunks
            int j = jo * 64 + lane;
            const float* srow = sums + g * 512;
            float acc = 0.f;
            for (int k = wv * 128; k < wv * 128 + 128; ++k)   // 4 waves split k
                acc = fmaf(srow[k], Wo[k * 512 + j], acc);
            part[wv][lane] = acc;
            __syncthreads();
            if (tid < 64) {
                float s = part[0][tid] + part[1][tid] + part[2][tid] + part[3][tid];
                float c = (float)(gstart[g + 1] - gstart[g]);
                float inv = 1.f / (c > 0.f ? c : 1.f);
                out[g * 512 + jo * 64 + tid] = fmaf(s, inv, bo[jo * 64 + tid]);
            }
            __syncthreads();   // part reused next iteration
        }
    }
}

extern "C" void kernel_launch(void* const* d_in, const int* in_sizes, int n_in,
                              void* d_out, int out_size, void* d_ws, size_t ws_size,
                              hipStream_t stream) {
    const float* x     = (const float*)d_in[0];
    const int*   ei    = (const int*)d_in[1];    // [2, NE]
    const int*   batch = (const int*)d_in[2];    // [NN] sorted
    const float* W1    = (const float*)d_in[3];
    const float* as1   = (const float*)d_in[4];
    const float* ad1   = (const float*)d_in[5];
    const float* b1    = (const float*)d_in[6];
    const float* W2    = (const float*)d_in[7];
    const float* as2   = (const float*)d_in[8];
    const float* ad2   = (const float*)d_in[9];
    const float* b2    = (const float*)d_in[10];
    const float* Wo    = (const float*)d_in[11];
    const float* bo    = (const float*)d_in[12];
    float* out = (float*)d_out;

    // ---- workspace arena (4-byte units) ----
    float* w = (float*)d_ws;
    unsigned short* h1bf  = (unsigned short*)(w + 0);        // 640,000 units
    float* al_s1 = w + 640000;     // 160,000
    float* al_d1 = w + 800000;     // 160,000
    unsigned short* o1bf  = (unsigned short*)(w + 960000);   // 640,000 units (16B aligned)
    unsigned short* W2bfT = (unsigned short*)(w + 1600000);  // 16,384 units (16B aligned)
    float* a2ps  = w + 1616384;    // 64
    float* a2pd  = w + 1616448;    // 64
    float* al_s2 = w + 1616512;    // 20,000
    float* al_d2 = w + 1636512;    // 20,000
    int*   gstart = (int*)(w + 1656512);   // 65
    int*   csr64  = (int*)(w + 1656580);   // 1,280,000 (fixed-stride CSR, 64 slots/node)
    float* sums   = w + 2936580;           // 32,768 (16B aligned; zeroed in stage 0)
    int*   deg    = (int*)(w + 2969348);   // 20,000 (zeroed in stage 0)
    // end: 2,989,348 units ≈ 12.0 MB

    // Grid sized from the occupancy query so the cooperative launch is always valid.
    static int g_grid = 0;
    if (g_grid == 0) {
        hipDeviceProp_t prop;
        hipGetDeviceProperties(&prop, 0);
        int maxBlk = 0;
        hipOccupancyMaxActiveBlocksPerMultiprocessor(&maxBlk, k_all, TPB, 0);
        if (maxBlk < 1) maxBlk = 1;
        long g = (long)maxBlk * (long)prop.multiProcessorCount;
        if (g > 2048) g = 2048;   // enough TLP; beyond this the loops just shrink
        if (g < 64)   g = 64;
        g_grid = (int)g;
    }

    void* args[] = {
        (void*)&ei, (void*)&x, (void*)&batch, (void*)&W1, (void*)&as1, (void*)&ad1,
        (void*)&b1, (void*)&W2, (void*)&as2, (void*)&ad2, (void*)&b2, (void*)&Wo,
        (void*)&bo, (void*)&deg, (void*)&csr64, (void*)&W2bfT, (void*)&a2ps,
        (void*)&a2pd, (void*)&h1bf, (void*)&al_s1, (void*)&al_d1, (void*)&o1bf,
        (void*)&al_s2, (void*)&al_d2, (void*)&gstart, (void*)&sums, (void*)&out
    };
    hipLaunchCooperativeKernel((const void*)k_all, dim3(g_grid), dim3(TPB), args, 0, stream);
}

// Round 6
// 259.221 us; speedup vs baseline: 2.3322x; 1.6353x over previous
//
#include <hip/hip_runtime.h>
#include <math.h>

#define NN 20000      // nodes
#define NE 320000     // edges (without self loops)
#define NT 340000     // edges + self loops
#define NG 64         // graphs
#define HB 1329       // ceil(NT/256) fused hist+scatter blocks
#define CB 128        // W2->bf16 transpose blocks
#define AB 2          // a2p GEMV blocks
#define NB2 (NN / 16) // 1250 l2gemm blocks
#define NFIN 256      // last arrivals that also do the final GEMM (64 g x 4 j-chunks)

using short8  = __attribute__((ext_vector_type(8))) short;   // 8 x bf16 (4 VGPRs)
using float4v = __attribute__((ext_vector_type(4))) float;   // MFMA accumulator

__device__ __forceinline__ float lrelu(float v) { return v > 0.f ? v : 0.2f * v; }
__device__ __forceinline__ float elu1(float v)  { return v > 0.f ? v : (expf(v) - 1.f); }
__device__ __forceinline__ float bflo(unsigned u) { return __uint_as_float(u << 16); }
__device__ __forceinline__ float bfhi(unsigned u) { return __uint_as_float(u & 0xFFFF0000u); }
__device__ __forceinline__ unsigned short f2bf(float f) {
    unsigned u = __float_as_uint(f);
    u += 0x7FFFu + ((u >> 16) & 1u);   // round to nearest even
    return (unsigned short)(u >> 16);
}

#define ACC8(ex, hv) \
    acc[0] = fmaf(ex, bflo(hv.x), acc[0]); \
    acc[1] = fmaf(ex, bfhi(hv.x), acc[1]); \
    acc[2] = fmaf(ex, bflo(hv.y), acc[2]); \
    acc[3] = fmaf(ex, bfhi(hv.y), acc[3]); \
    acc[4] = fmaf(ex, bflo(hv.z), acc[4]); \
    acc[5] = fmaf(ex, bfhi(hv.z), acc[5]); \
    acc[6] = fmaf(ex, bflo(hv.w), acc[6]); \
    acc[7] = fmaf(ex, bfhi(hv.w), acc[7]);

// ---------- D2: fused prep (round-1-proven; sums zeroing moved into the memset) ----------
// blocks [0,HB): hist+scatter in ONE pass (rank from the degree atomic; fixed stride 64).
// [HB,HB+CB): W2 -> bf16 transpose.  [+AB): a2p GEMVs.  [+1): gstart.  rest: x@W1 + logits.
__global__ void k_prep(const int* __restrict__ ei, int* __restrict__ deg,
                       int* __restrict__ csr64,
                       const float* __restrict__ W2, unsigned short* __restrict__ W2bfT,
                       const float* __restrict__ as2, const float* __restrict__ ad2,
                       float* __restrict__ a2ps, float* __restrict__ a2pd,
                       const float* __restrict__ x, const float* __restrict__ W1,
                       const float* __restrict__ as1, const float* __restrict__ ad1,
                       unsigned short* __restrict__ h1bf, float* __restrict__ al_s,
                       float* __restrict__ al_d,
                       const int* __restrict__ batch, int* __restrict__ gstart) {
    int tid = threadIdx.x;
    int b = blockIdx.x;
    if (b < HB) {
        int t = b * 256 + tid;
        if (t < NT) {
            int s, d;
            if (t < NE) { s = ei[t]; d = ei[NE + t]; }
            else        { s = d = t - NE; }            // self loop
            int r = atomicAdd(&deg[d], 1);             // rank within dst row
            if (r < 64) csr64[(d << 6) + r] = s;
        }
        return;
    }
    if (b < HB + CB) {
        int t = (b - HB) * 256 + tid;  // t = n*64 + k
        int k = t & 63, n = t >> 6;
        W2bfT[t] = f2bf(W2[k * 512 + n]);
        return;
    }
    if (b < HB + CB + AB) {
        // a2p[k] = sum_j W2[k][j] * a[j]   (64x512 GEMV)
        __shared__ float pp[4][64];
        const float* av = (b == HB + CB) ? as2 : ad2;
        float* outp     = (b == HB + CB) ? a2ps : a2pd;
        int k = tid & 63, seg = tid >> 6;
        float s = 0.f;
        for (int j = seg * 128; j < seg * 128 + 128; ++j)
            s = fmaf(W2[k * 512 + j], av[j], s);
        pp[seg][k] = s;
        __syncthreads();
        if (tid < 64) outp[tid] = pp[0][tid] + pp[1][tid] + pp[2][tid] + pp[3][tid];
        return;
    }
    if (b == HB + CB + AB) {
        if (tid <= NG) {               // per-graph node-range starts (batch is sorted)
            int lo = 0, hi = NN;
            while (lo < hi) {
                int mid = (lo + hi) >> 1;
                if (batch[mid] < tid) lo = mid + 1; else hi = mid;
            }
            gstart[tid] = lo;
        }
        return;
    }
    int n = (b - HB - CB - AB - 1) * 4 + (tid >> 6);
    int j = tid & 63;
    float x0 = x[n * 3 + 0], x1 = x[n * 3 + 1], x2 = x[n * 3 + 2];
    float v = fmaf(x0, W1[j], fmaf(x1, W1[64 + j], x2 * W1[128 + j]));
    h1bf[n * 64 + j] = f2bf(v);
    float ps = v * as1[j];
    float pd = v * ad1[j];
    for (int o = 4; o >= 1; o >>= 1) {
        ps += __shfl_xor(ps, o, 8);
        pd += __shfl_xor(pd, o, 8);
    }
    if ((j & 7) == 0) {
        al_s[n * 8 + (j >> 3)] = ps;
        al_d[n * 8 + (j >> 3)] = pd;
    }
}

// ---------- D3: fused layer-1 softmax+aggregate + elu; layer-2 logits (round-1-proven) ----
__global__ void k_l1(const int* __restrict__ deg, const int* __restrict__ csr64,
                     const float* __restrict__ al_s, const float* __restrict__ al_d,
                     const unsigned short* __restrict__ h1bf, const float* __restrict__ b1,
                     const float* __restrict__ a2ps, const float* __restrict__ a2pd,
                     unsigned short* __restrict__ o1bf, float* __restrict__ al_s2,
                     float* __restrict__ al_d2) {
    int nb = threadIdx.x >> 6;
    int n = blockIdx.x * 4 + nb;
    int lane = threadIdx.x & 63;
    int e8 = lane >> 3, c8 = lane & 7;   // edge slot, head
    int dg = deg[n]; dg = dg < 64 ? dg : 64;
    int sAll = csr64[(n << 6) + (lane < dg ? lane : 0)];
    float ald = al_d[n * 8 + c8];
    float acc[8] = {0.f, 0.f, 0.f, 0.f, 0.f, 0.f, 0.f, 0.f};
    float dsum = 0.f;
    for (int base = 0; base < dg; base += 16) {
        int sA = __shfl(sAll, base + e8, 64);
        int sB = __shfl(sAll, base + 8 + e8, 64);
        float exA = 0.f, exB = 0.f;
        if (base + e8 < dg)     exA = __expf(lrelu(al_s[sA * 8 + c8] + ald));
        if (base + 8 + e8 < dg) exB = __expf(lrelu(al_s[sB * 8 + c8] + ald));
        dsum += exA + exB;
        uint4 hA = *(const uint4*)(h1bf + sA * 64 + c8 * 8);
        uint4 hB = *(const uint4*)(h1bf + sB * 64 + c8 * 8);
        ACC8(exA, hA);
        ACC8(exB, hB);
    }
#pragma unroll
    for (int o = 32; o >= 8; o >>= 1) {
#pragma unroll
        for (int k = 0; k < 8; ++k) acc[k] += __shfl_xor(acc[k], o, 64);
        dsum += __shfl_xor(dsum, o, 64);
    }
    if (e8 == 0) {   // lanes 0..7: finalize head c8's 8 channels
        float inv = 1.f / dsum;
        const float* bp = b1 + c8 * 8;
        float v[8];
#pragma unroll
        for (int k = 0; k < 8; ++k) v[k] = elu1(acc[k] * inv + bp[k]);
        uint4 pk;
        pk.x = (unsigned)f2bf(v[0]) | ((unsigned)f2bf(v[1]) << 16);
        pk.y = (unsigned)f2bf(v[2]) | ((unsigned)f2bf(v[3]) << 16);
        pk.z = (unsigned)f2bf(v[4]) | ((unsigned)f2bf(v[5]) << 16);
        pk.w = (unsigned)f2bf(v[6]) | ((unsigned)f2bf(v[7]) << 16);
        *(uint4*)(o1bf + n * 64 + c8 * 8) = pk;
        float ps = 0.f, pd = 0.f;
        const float* asp = a2ps + c8 * 8;
        const float* adp = a2pd + c8 * 8;
#pragma unroll
        for (int k = 0; k < 8; ++k) {
            ps = fmaf(v[k], asp[k], ps);
            pd = fmaf(v[k], adp[k], pd);
        }
        for (int o = 4; o >= 1; o >>= 1) {
            ps += __shfl_xor(ps, o, 8);
            pd += __shfl_xor(pd, o, 8);
        }
        if (c8 == 0) { al_s2[n] = ps; al_d2[n] = pd; }
    }
}

// ---------- D4: layer-2 softmax-agg + MFMA @W2 + elu + pool + (last-arrival) final GEMM ---
// Round-1-proven body. After the sums atomics, each block bumps an arrival counter; the
// LAST NFIN arrivals each claim one (g, j-chunk) of out = (sums/cnt) @ Wo + bo, spin until
// all 1250 blocks arrived (short spins: they ARE the last arrivals; <=256 spinners can
// never fill residency, so no deadlock), then read sums with agent-scope atomic loads.
__global__ void k_l2gemm(const int* __restrict__ deg, const int* __restrict__ csr64,
                         const float* __restrict__ al_s2, const float* __restrict__ al_d2,
                         const unsigned short* __restrict__ o1bf,
                         const unsigned short* __restrict__ W2bfT,
                         const float* __restrict__ b2, const int* __restrict__ batch,
                         float* __restrict__ sums,
                         const float* __restrict__ Wo, const float* __restrict__ bo,
                         const int* __restrict__ gstart, int* __restrict__ done,
                         float* __restrict__ out) {
    __shared__ __align__(16) char smraw[4096];   // lagg[16][72]u16 | sp[512]f32+part[4][128]f32
    __shared__ int s_old;
    unsigned short (*lagg)[72] = (unsigned short(*)[72])smraw;   // padded rows: 144B stride
    int n0 = blockIdx.x * 16;
    int wv = threadIdx.x >> 6, lane = threadIdx.x & 63;
    int e8 = lane >> 3, c8 = lane & 7;
#pragma unroll
    for (int i = 0; i < 2; ++i) {
        int r = wv * 2 + i;
        int n = n0 + r;
        float ald = al_d2[n];
        int dg = deg[n]; dg = dg < 64 ? dg : 64;
        int sAll = csr64[(n << 6) + (lane < dg ? lane : 0)];
        float exAll = 0.f;
        if (lane < dg) exAll = __expf(lrelu(al_s2[sAll] + ald));
        float dsum = exAll;
        dsum += __shfl_xor(dsum, 1, 64);
        dsum += __shfl_xor(dsum, 2, 64);
        dsum += __shfl_xor(dsum, 4, 64);
        float acc[8] = {0.f, 0.f, 0.f, 0.f, 0.f, 0.f, 0.f, 0.f};
        for (int base = 0; base < dg; base += 16) {
            int sA   = __shfl(sAll, base + e8, 64);
            int sB   = __shfl(sAll, base + 8 + e8, 64);
            float exA = __shfl(exAll, base + e8, 64);      // 0 for invalid slots
            float exB = __shfl(exAll, base + 8 + e8, 64);
            uint4 hA = *(const uint4*)(o1bf + sA * 64 + c8 * 8);
            uint4 hB = *(const uint4*)(o1bf + sB * 64 + c8 * 8);
            ACC8(exA, hA);
            ACC8(exB, hB);
        }
#pragma unroll
        for (int o = 32; o >= 8; o >>= 1) {
#pragma unroll
            for (int k = 0; k < 8; ++k) acc[k] += __shfl_xor(acc[k], o, 64);
            dsum += __shfl_xor(dsum, o, 64);
        }
        if (e8 == 0) {   // lanes 0..7 pack channels c8*8..+7
            float inv = 1.f / dsum;
            uint4 pk;
            pk.x = (unsigned)f2bf(acc[0] * inv) | ((unsigned)f2bf(acc[1] * inv) << 16);
            pk.y = (unsigned)f2bf(acc[2] * inv) | ((unsigned)f2bf(acc[3] * inv) << 16);
            pk.z = (unsigned)f2bf(acc[4] * inv) | ((unsigned)f2bf(acc[5] * inv) << 16);
            pk.w = (unsigned)f2bf(acc[6] * inv) | ((unsigned)f2bf(acc[7] * inv) << 16);
            *(uint4*)&lagg[r][c8 * 8] = pk;
        }
    }
    __syncthreads();
    // phase B: A[m=lane&15][k=quad*8+j] from LDS; B[k][n=lane&15] from W2bfT (n-major).
    int mcol = lane & 15;
    int q = lane >> 4;
    short8 a0 = *(const short8*)&lagg[mcol][q * 8];
    short8 a1 = *(const short8*)&lagg[mcol][32 + q * 8];
    int gmin = batch[n0], gmax = batch[n0 + 15];
    int batchq[4];
#pragma unroll
    for (int r = 0; r < 4; ++r) batchq[r] = batch[n0 + q * 4 + r];
#pragma unroll
    for (int t = 0; t < 4; ++t) {
        int c = wv * 64 + t * 16 + mcol;
        const unsigned short* bp = W2bfT + c * 64 + q * 8;
        short8 b0 = *(const short8*)bp;
        short8 b1v = *(const short8*)(bp + 32);
        float4v macc = {0.f, 0.f, 0.f, 0.f};
        macc = __builtin_amdgcn_mfma_f32_16x16x32_bf16(a0, b0, macc, 0, 0, 0);
        macc = __builtin_amdgcn_mfma_f32_16x16x32_bf16(a1, b1v, macc, 0, 0, 0);
        float bias = b2[c];
        float val[4];
#pragma unroll
        for (int r = 0; r < 4; ++r) val[r] = elu1(macc[r] + bias);
        for (int g = gmin; g <= gmax; ++g) {
            float s = 0.f;
#pragma unroll
            for (int r = 0; r < 4; ++r) s += (batchq[r] == g) ? val[r] : 0.f;
            s += __shfl_xor(s, 16, 64);   // reduce across the 4 quads
            s += __shfl_xor(s, 32, 64);
            if (q == 0) atomicAdd(&sums[g * 512 + c], s);
        }
    }

    // ---- arrival counter; last NFIN blocks compute the final GEMM ----
    __syncthreads();                                  // drains this block's vmem (atomics)
    if (threadIdx.x == 0) {
        __threadfence();                              // release
        s_old = atomicAdd(done, 1);
    }
    __syncthreads();
    int claim = s_old - (NB2 - NFIN);
    if (claim < 0) return;
    if (threadIdx.x == 0) {
        while (__hip_atomic_load(done, __ATOMIC_ACQUIRE, __HIP_MEMORY_SCOPE_AGENT) < NB2)
            __builtin_amdgcn_s_sleep(2);
    }
    __syncthreads();
    __threadfence();                                  // acquire
    float* sp = (float*)smraw;                        // [512]
    float (*part)[128] = (float(*)[128])(smraw + 2048);  // [4][128]
    int g = claim >> 2, jo = claim & 3;               // 64 g x 4 chunks of 128 j
    const float* srow = sums + g * 512;
    for (int k = threadIdx.x; k < 512; k += 512)
        sp[k] = __hip_atomic_load(&srow[k], __ATOMIC_RELAXED, __HIP_MEMORY_SCOPE_AGENT);
    __syncthreads();
    int jj = threadIdx.x & 127;                       // j within chunk
    int kq = threadIdx.x >> 7;                        // k-quarter 0..3
    int j  = jo * 128 + jj;
    float acc = 0.f;
    for (int k = kq * 128; k < kq * 128 + 128; ++k)
        acc = fmaf(sp[k], Wo[k * 512 + j], acc);
    part[kq][jj] = acc;
    __syncthreads();
    if (threadIdx.x < 128) {
        float s = part[0][threadIdx.x] + part[1][threadIdx.x]
                + part[2][threadIdx.x] + part[3][threadIdx.x];
        float c = (float)(gstart[g + 1] - gstart[g]);
        float inv = 1.f / (c > 0.f ? c : 1.f);
        out[g * 512 + jo * 128 + threadIdx.x] = fmaf(s, inv, bo[jo * 128 + threadIdx.x]);
    }
}

extern "C" void kernel_launch(void* const* d_in, const int* in_sizes, int n_in,
                              void* d_out, int out_size, void* d_ws, size_t ws_size,
                              hipStream_t stream) {
    const float* x     = (const float*)d_in[0];
    const int*   ei    = (const int*)d_in[1];    // [2, NE]
    const int*   batch = (const int*)d_in[2];    // [NN] sorted
    const float* W1    = (const float*)d_in[3];
    const float* as1   = (const float*)d_in[4];
    const float* ad1   = (const float*)d_in[5];
    const float* b1    = (const float*)d_in[6];
    const float* W2    = (const float*)d_in[7];
    const float* as2   = (const float*)d_in[8];
    const float* ad2   = (const float*)d_in[9];
    const float* b2    = (const float*)d_in[10];
    const float* Wo    = (const float*)d_in[11];
    const float* bo    = (const float*)d_in[12];
    float* out = (float*)d_out;

    // ---- workspace arena (4-byte units) ----
    float* w = (float*)d_ws;
    unsigned short* h1bf  = (unsigned short*)(w + 0);        // 640,000 units
    float* al_s1 = w + 640000;     // 160,000
    float* al_d1 = w + 800000;     // 160,000
    unsigned short* o1bf  = (unsigned short*)(w + 960000);   // 640,000 units (16B aligned)
    unsigned short* W2bfT = (unsigned short*)(w + 1600000);  // 16,384 units (16B aligned)
    float* a2ps  = w + 1616384;    // 64
    float* a2pd  = w + 1616448;    // 64
    float* al_s2 = w + 1616512;    // 20,000
    float* al_d2 = w + 1636512;    // 20,000
    int*   gstart = (int*)(w + 1656512);   // 65
    int*   csr64  = (int*)(w + 1656580);   // 1,280,000 (fixed-stride CSR, 64 slots/node)
    // ---- zero-initialized region (one contiguous memset): sums | deg | done ----
    float* sums   = w + 2936580;           // 32,768 (16B aligned)
    int*   deg    = (int*)(w + 2969348);   // 20,000
    int*   done   = (int*)(w + 2989348);   // 4 (padded)
    // end: 2,989,352 units ≈ 12.0 MB

    hipMemsetAsync(sums, 0, (size_t)(32768 + 20000 + 4) * 4, stream);

    k_prep   <<<HB + CB + AB + 1 + NN / 4, 256, 0, stream>>>(
        ei, deg, csr64, W2, W2bfT, as2, ad2, a2ps, a2pd,
        x, W1, as1, ad1, h1bf, al_s1, al_d1, batch, gstart);
    k_l1     <<<NN / 4, 256, 0, stream>>>(deg, csr64, al_s1, al_d1, h1bf, b1,
                                          a2ps, a2pd, o1bf, al_s2, al_d2);
    k_l2gemm <<<NB2, 512, 0, stream>>>(deg, csr64, al_s2, al_d2, o1bf,
                                       W2bfT, b2, batch, sums,
                                       Wo, bo, gstart, done, out);
}

// Round 7
// 187.961 us; speedup vs baseline: 3.2164x; 1.3791x over previous
//
#include <hip/hip_runtime.h>
#include <math.h>

#define NN 20000      // nodes
#define NE 320000     // edges (without self loops)
#define NT 340000     // edges + self loops
#define NG 64         // graphs
#define HB 1329       // ceil(NT/256) fused hist+scatter blocks
#define CB 128        // W2->bf16 transpose blocks
#define AB 2          // a2p GEMV blocks
#define NB2 (NN / 16) // 1250 l2gemm blocks
#define NFIN 64       // last arrivals also do the final GEMM (1 graph each)

using short8  = __attribute__((ext_vector_type(8))) short;   // 8 x bf16 (4 VGPRs)
using float4v = __attribute__((ext_vector_type(4))) float;   // MFMA accumulator

__device__ __forceinline__ float lrelu(float v) { return v > 0.f ? v : 0.2f * v; }
__device__ __forceinline__ float elu1(float v)  { return v > 0.f ? v : (expf(v) - 1.f); }
__device__ __forceinline__ float bflo(unsigned u) { return __uint_as_float(u << 16); }
__device__ __forceinline__ float bfhi(unsigned u) { return __uint_as_float(u & 0xFFFF0000u); }
__device__ __forceinline__ unsigned short f2bf(float f) {
    unsigned u = __float_as_uint(f);
    u += 0x7FFFu + ((u >> 16) & 1u);   // round to nearest even
    return (unsigned short)(u >> 16);
}

#define ACC8(ex, hv) \
    acc[0] = fmaf(ex, bflo(hv.x), acc[0]); \
    acc[1] = fmaf(ex, bfhi(hv.x), acc[1]); \
    acc[2] = fmaf(ex, bflo(hv.y), acc[2]); \
    acc[3] = fmaf(ex, bfhi(hv.y), acc[3]); \
    acc[4] = fmaf(ex, bflo(hv.z), acc[4]); \
    acc[5] = fmaf(ex, bfhi(hv.z), acc[5]); \
    acc[6] = fmaf(ex, bflo(hv.w), acc[6]); \
    acc[7] = fmaf(ex, bfhi(hv.w), acc[7]);

// ---------- D2: fused prep (round-1-proven) ----------
__global__ void k_prep(const int* __restrict__ ei, int* __restrict__ deg,
                       int* __restrict__ csr64,
                       const float* __restrict__ W2, unsigned short* __restrict__ W2bfT,
                       const float* __restrict__ as2, const float* __restrict__ ad2,
                       float* __restrict__ a2ps, float* __restrict__ a2pd,
                       const float* __restrict__ x, const float* __restrict__ W1,
                       const float* __restrict__ as1, const float* __restrict__ ad1,
                       unsigned short* __restrict__ h1bf, float* __restrict__ al_s,
                       float* __restrict__ al_d,
                       const int* __restrict__ batch, int* __restrict__ gstart) {
    int tid = threadIdx.x;
    int b = blockIdx.x;
    if (b < HB) {
        int t = b * 256 + tid;
        if (t < NT) {
            int s, d;
            if (t < NE) { s = ei[t]; d = ei[NE + t]; }
            else        { s = d = t - NE; }            // self loop
            int r = atomicAdd(&deg[d], 1);             // rank within dst row
            if (r < 64) csr64[(d << 6) + r] = s;
        }
        return;
    }
    if (b < HB + CB) {
        int t = (b - HB) * 256 + tid;  // t = n*64 + k
        int k = t & 63, n = t >> 6;
        W2bfT[t] = f2bf(W2[k * 512 + n]);
        return;
    }
    if (b < HB + CB + AB) {
        // a2p[k] = sum_j W2[k][j] * a[j]   (64x512 GEMV)
        __shared__ float pp[4][64];
        const float* av = (b == HB + CB) ? as2 : ad2;
        float* outp     = (b == HB + CB) ? a2ps : a2pd;
        int k = tid & 63, seg = tid >> 6;
        float s = 0.f;
        for (int j = seg * 128; j < seg * 128 + 128; ++j)
            s = fmaf(W2[k * 512 + j], av[j], s);
        pp[seg][k] = s;
        __syncthreads();
        if (tid < 64) outp[tid] = pp[0][tid] + pp[1][tid] + pp[2][tid] + pp[3][tid];
        return;
    }
    if (b == HB + CB + AB) {
        if (tid <= NG) {               // per-graph node-range starts (batch is sorted)
            int lo = 0, hi = NN;
            while (lo < hi) {
                int mid = (lo + hi) >> 1;
                if (batch[mid] < tid) lo = mid + 1; else hi = mid;
            }
            gstart[tid] = lo;
        }
        return;
    }
    int n = (b - HB - CB - AB - 1) * 4 + (tid >> 6);
    int j = tid & 63;
    float x0 = x[n * 3 + 0], x1 = x[n * 3 + 1], x2 = x[n * 3 + 2];
    float v = fmaf(x0, W1[j], fmaf(x1, W1[64 + j], x2 * W1[128 + j]));
    h1bf[n * 64 + j] = f2bf(v);
    float ps = v * as1[j];
    float pd = v * ad1[j];
    for (int o = 4; o >= 1; o >>= 1) {
        ps += __shfl_xor(ps, o, 8);
        pd += __shfl_xor(pd, o, 8);
    }
    if ((j & 7) == 0) {
        al_s[n * 8 + (j >> 3)] = ps;
        al_d[n * 8 + (j >> 3)] = pd;
    }
}

// ---------- D3: fused layer-1 softmax+aggregate + elu; layer-2 logits (round-1-proven) ----
__global__ void k_l1(const int* __restrict__ deg, const int* __restrict__ csr64,
                     const float* __restrict__ al_s, const float* __restrict__ al_d,
                     const unsigned short* __restrict__ h1bf, const float* __restrict__ b1,
                     const float* __restrict__ a2ps, const float* __restrict__ a2pd,
                     unsigned short* __restrict__ o1bf, float* __restrict__ al_s2,
                     float* __restrict__ al_d2) {
    int nb = threadIdx.x >> 6;
    int n = blockIdx.x * 4 + nb;
    int lane = threadIdx.x & 63;
    int e8 = lane >> 3, c8 = lane & 7;   // edge slot, head
    int dg = deg[n]; dg = dg < 64 ? dg : 64;
    int sAll = csr64[(n << 6) + (lane < dg ? lane : 0)];
    float ald = al_d[n * 8 + c8];
    float acc[8] = {0.f, 0.f, 0.f, 0.f, 0.f, 0.f, 0.f, 0.f};
    float dsum = 0.f;
    for (int base = 0; base < dg; base += 16) {
        int sA = __shfl(sAll, base + e8, 64);
        int sB = __shfl(sAll, base + 8 + e8, 64);
        float exA = 0.f, exB = 0.f;
        if (base + e8 < dg)     exA = __expf(lrelu(al_s[sA * 8 + c8] + ald));
        if (base + 8 + e8 < dg) exB = __expf(lrelu(al_s[sB * 8 + c8] + ald));
        dsum += exA + exB;
        uint4 hA = *(const uint4*)(h1bf + sA * 64 + c8 * 8);
        uint4 hB = *(const uint4*)(h1bf + sB * 64 + c8 * 8);
        ACC8(exA, hA);
        ACC8(exB, hB);
    }
#pragma unroll
    for (int o = 32; o >= 8; o >>= 1) {
#pragma unroll
        for (int k = 0; k < 8; ++k) acc[k] += __shfl_xor(acc[k], o, 64);
        dsum += __shfl_xor(dsum, o, 64);
    }
    if (e8 == 0) {   // lanes 0..7: finalize head c8's 8 channels
        float inv = 1.f / dsum;
        const float* bp = b1 + c8 * 8;
        float v[8];
#pragma unroll
        for (int k = 0; k < 8; ++k) v[k] = elu1(acc[k] * inv + bp[k]);
        uint4 pk;
        pk.x = (unsigned)f2bf(v[0]) | ((unsigned)f2bf(v[1]) << 16);
        pk.y = (unsigned)f2bf(v[2]) | ((unsigned)f2bf(v[3]) << 16);
        pk.z = (unsigned)f2bf(v[4]) | ((unsigned)f2bf(v[5]) << 16);
        pk.w = (unsigned)f2bf(v[6]) | ((unsigned)f2bf(v[7]) << 16);
        *(uint4*)(o1bf + n * 64 + c8 * 8) = pk;
        float ps = 0.f, pd = 0.f;
        const float* asp = a2ps + c8 * 8;
        const float* adp = a2pd + c8 * 8;
#pragma unroll
        for (int k = 0; k < 8; ++k) {
            ps = fmaf(v[k], asp[k], ps);
            pd = fmaf(v[k], adp[k], pd);
        }
        for (int o = 4; o >= 1; o >>= 1) {
            ps += __shfl_xor(ps, o, 8);
            pd += __shfl_xor(pd, o, 8);
        }
        if (c8 == 0) { al_s2[n] = ps; al_d2[n] = pd; }
    }
}

// ---------- D4: layer-2 softmax-agg + MFMA @W2 + elu + pool + (last-arrival) final GEMM ---
// Arrival counter; last NFIN=64 arrivals each compute one graph of out = (sums/cnt)@Wo+bo.
// SPIN FIX vs round 6: poll with RELAXED agent atomic loads (no per-poll cache
// invalidation -- round 6's ACQUIRE polls emitted L1/L2 invalidates every ~128 cycles,
// evicting co-resident workers' o1bf/csr64 working set: FETCH 15.4MB, tail ~130us) and
// s_sleep(64) (~4k cycles/poll). No acquire needed after the loop: sums is read via
// agent-scope ATOMIC loads (bypass stale caches); Wo/bo/gstart predate the dispatch.
__global__ void k_l2gemm(const int* __restrict__ deg, const int* __restrict__ csr64,
                         const float* __restrict__ al_s2, const float* __restrict__ al_d2,
                         const unsigned short* __restrict__ o1bf,
                         const unsigned short* __restrict__ W2bfT,
                         const float* __restrict__ b2, const int* __restrict__ batch,
                         float* __restrict__ sums,
                         const float* __restrict__ Wo, const float* __restrict__ bo,
                         const int* __restrict__ gstart, int* __restrict__ done,
                         float* __restrict__ out) {
    __shared__ __align__(16) char smraw[2304];   // lagg[16][72]u16, reused as sp[512]f32
    __shared__ int s_old;
    unsigned short (*lagg)[72] = (unsigned short(*)[72])smraw;   // padded rows: 144B stride
    int n0 = blockIdx.x * 16;
    int wv = threadIdx.x >> 6, lane = threadIdx.x & 63;
    int e8 = lane >> 3, c8 = lane & 7;
#pragma unroll
    for (int i = 0; i < 2; ++i) {
        int r = wv * 2 + i;
        int n = n0 + r;
        float ald = al_d2[n];
        int dg = deg[n]; dg = dg < 64 ? dg : 64;
        int sAll = csr64[(n << 6) + (lane < dg ? lane : 0)];
        float exAll = 0.f;
        if (lane < dg) exAll = __expf(lrelu(al_s2[sAll] + ald));
        float dsum = exAll;
        dsum += __shfl_xor(dsum, 1, 64);
        dsum += __shfl_xor(dsum, 2, 64);
        dsum += __shfl_xor(dsum, 4, 64);
        float acc[8] = {0.f, 0.f, 0.f, 0.f, 0.f, 0.f, 0.f, 0.f};
        for (int base = 0; base < dg; base += 16) {
            int sA   = __shfl(sAll, base + e8, 64);
            int sB   = __shfl(sAll, base + 8 + e8, 64);
            float exA = __shfl(exAll, base + e8, 64);      // 0 for invalid slots
            float exB = __shfl(exAll, base + 8 + e8, 64);
            uint4 hA = *(const uint4*)(o1bf + sA * 64 + c8 * 8);
            uint4 hB = *(const uint4*)(o1bf + sB * 64 + c8 * 8);
            ACC8(exA, hA);
            ACC8(exB, hB);
        }
#pragma unroll
        for (int o = 32; o >= 8; o >>= 1) {
#pragma unroll
            for (int k = 0; k < 8; ++k) acc[k] += __shfl_xor(acc[k], o, 64);
            dsum += __shfl_xor(dsum, o, 64);
        }
        if (e8 == 0) {   // lanes 0..7 pack channels c8*8..+7
            float inv = 1.f / dsum;
            uint4 pk;
            pk.x = (unsigned)f2bf(acc[0] * inv) | ((unsigned)f2bf(acc[1] * inv) << 16);
            pk.y = (unsigned)f2bf(acc[2] * inv) | ((unsigned)f2bf(acc[3] * inv) << 16);
            pk.z = (unsigned)f2bf(acc[4] * inv) | ((unsigned)f2bf(acc[5] * inv) << 16);
            pk.w = (unsigned)f2bf(acc[6] * inv) | ((unsigned)f2bf(acc[7] * inv) << 16);
            *(uint4*)&lagg[r][c8 * 8] = pk;
        }
    }
    __syncthreads();
    // phase B: A[m=lane&15][k=quad*8+j] from LDS; B[k][n=lane&15] from W2bfT (n-major).
    int mcol = lane & 15;
    int q = lane >> 4;
    short8 a0 = *(const short8*)&lagg[mcol][q * 8];
    short8 a1 = *(const short8*)&lagg[mcol][32 + q * 8];
    int gmin = batch[n0], gmax = batch[n0 + 15];
    int batchq[4];
#pragma unroll
    for (int r = 0; r < 4; ++r) batchq[r] = batch[n0 + q * 4 + r];
#pragma unroll
    for (int t = 0; t < 4; ++t) {
        int c = wv * 64 + t * 16 + mcol;
        const unsigned short* bp = W2bfT + c * 64 + q * 8;
        short8 b0 = *(const short8*)bp;
        short8 b1v = *(const short8*)(bp + 32);
        float4v macc = {0.f, 0.f, 0.f, 0.f};
        macc = __builtin_amdgcn_mfma_f32_16x16x32_bf16(a0, b0, macc, 0, 0, 0);
        macc = __builtin_amdgcn_mfma_f32_16x16x32_bf16(a1, b1v, macc, 0, 0, 0);
        float bias = b2[c];
        float val[4];
#pragma unroll
        for (int r = 0; r < 4; ++r) val[r] = elu1(macc[r] + bias);
        for (int g = gmin; g <= gmax; ++g) {
            float s = 0.f;
#pragma unroll
            for (int r = 0; r < 4; ++r) s += (batchq[r] == g) ? val[r] : 0.f;
            s += __shfl_xor(s, 16, 64);   // reduce across the 4 quads
            s += __shfl_xor(s, 32, 64);
            if (q == 0) atomicAdd(&sums[g * 512 + c], s);
        }
    }

    // ---- arrival counter; last NFIN blocks compute the final GEMM ----
    __syncthreads();                                  // vmcnt(0): sums atomics issued/complete
    if (threadIdx.x == 0) {
        __threadfence();                              // release
        s_old = atomicAdd(done, 1);
    }
    __syncthreads();
    int claim = s_old - (NB2 - NFIN);
    if (claim < 0) return;
    if (threadIdx.x == 0) {
        // RELAXED poll: reads through to the coherence point without invalidating caches.
        while (__hip_atomic_load(done, __ATOMIC_RELAXED, __HIP_MEMORY_SCOPE_AGENT) < NB2)
            __builtin_amdgcn_s_sleep(64);             // ~4k cycles between polls
    }
    __syncthreads();
    // finisher: one graph per block.  out[g][j] = (sums[g]/cnt[g]) @ Wo[:,j] + bo[j]
    float* sp = (float*)smraw;                        // [512] (lagg no longer needed)
    int g = claim;
    const float* srow = sums + g * 512;
    sp[threadIdx.x] = __hip_atomic_load(&srow[threadIdx.x],
                                        __ATOMIC_RELAXED, __HIP_MEMORY_SCOPE_AGENT);
    __syncthreads();
    int j = threadIdx.x;                              // 512 threads = 512 columns
    float acc = 0.f;
    for (int k = 0; k < 512; ++k)                     // sp[k]: LDS broadcast; Wo row: coalesced
        acc = fmaf(sp[k], Wo[k * 512 + j], acc);
    float c = (float)(gstart[g + 1] - gstart[g]);
    float inv = 1.f / (c > 0.f ? c : 1.f);
    out[g * 512 + j] = fmaf(acc, inv, bo[j]);
}

extern "C" void kernel_launch(void* const* d_in, const int* in_sizes, int n_in,
                              void* d_out, int out_size, void* d_ws, size_t ws_size,
                              hipStream_t stream) {
    const float* x     = (const float*)d_in[0];
    const int*   ei    = (const int*)d_in[1];    // [2, NE]
    const int*   batch = (const int*)d_in[2];    // [NN] sorted
    const float* W1    = (const float*)d_in[3];
    const float* as1   = (const float*)d_in[4];
    const float* ad1   = (const float*)d_in[5];
    const float* b1    = (const float*)d_in[6];
    const float* W2    = (const float*)d_in[7];
    const float* as2   = (const float*)d_in[8];
    const float* ad2   = (const float*)d_in[9];
    const float* b2    = (const float*)d_in[10];
    const float* Wo    = (const float*)d_in[11];
    const float* bo    = (const float*)d_in[12];
    float* out = (float*)d_out;

    // ---- workspace arena (4-byte units) ----
    float* w = (float*)d_ws;
    unsigned short* h1bf  = (unsigned short*)(w + 0);        // 640,000 units
    float* al_s1 = w + 640000;     // 160,000
    float* al_d1 = w + 800000;     // 160,000
    unsigned short* o1bf  = (unsigned short*)(w + 960000);   // 640,000 units (16B aligned)
    unsigned short* W2bfT = (unsigned short*)(w + 1600000);  // 16,384 units (16B aligned)
    float* a2ps  = w + 1616384;    // 64
    float* a2pd  = w + 1616448;    // 64
    float* al_s2 = w + 1616512;    // 20,000
    float* al_d2 = w + 1636512;    // 20,000
    int*   gstart = (int*)(w + 1656512);   // 65
    int*   csr64  = (int*)(w + 1656580);   // 1,280,000 (fixed-stride CSR, 64 slots/node)
    // ---- zero-initialized region (one contiguous memset): sums | deg | done ----
    float* sums   = w + 2936580;           // 32,768 (16B aligned)
    int*   deg    = (int*)(w + 2969348);   // 20,000
    int*   done   = (int*)(w + 2989348);   // 4 (padded)
    // end: 2,989,352 units ≈ 12.0 MB

    hipMemsetAsync(sums, 0, (size_t)(32768 + 20000 + 4) * 4, stream);

    k_prep   <<<HB + CB + AB + 1 + NN / 4, 256, 0, stream>>>(
        ei, deg, csr64, W2, W2bfT, as2, ad2, a2ps, a2pd,
        x, W1, as1, ad1, h1bf, al_s1, al_d1, batch, gstart);
    k_l1     <<<NN / 4, 256, 0, stream>>>(deg, csr64, al_s1, al_d1, h1bf, b1,
                                          a2ps, a2pd, o1bf, al_s2, al_d2);
    k_l2gemm <<<NB2, 512, 0, stream>>>(deg, csr64, al_s2, al_d2, o1bf,
                                       W2bfT, b2, batch, sums,
                                       Wo, bo, gstart, done, out);
}